// Round 1
// baseline (6970.273 us; speedup 1.0000x reference)
//
#include <hip/hip_runtime.h>
#include <hip/hip_bf16.h>

// Problem constants (VectorQuantizer: z [32,1024,768] f32, emb [8192,768] f32)
constexpr int D  = 768;     // feature dim
constexpr int NE = 8192;    // number of codes
constexpr int NR = 32768;   // number of rows (32*1024)
constexpr int BM = 64;      // rows per block
constexpr int BN = 128;     // codes per tile
constexpr int BK = 16;      // k-chunk
constexpr float EPSV = 1e-6f;

// ---------------------------------------------------------------------------
// Kernel 0: per-code squared norms. One wave per code, 4 codes per block.
// ---------------------------------------------------------------------------
__global__ __launch_bounds__(256) void e2_kernel(const float* __restrict__ emb,
                                                 float* __restrict__ e2) {
  const int wave = threadIdx.x >> 6;
  const int lane = threadIdx.x & 63;
  const int code = (blockIdx.x << 2) + wave;
  const float4* row4 = reinterpret_cast<const float4*>(emb + (size_t)code * D);
  float s = 0.f;
#pragma unroll
  for (int i = 0; i < 3; ++i) {              // 192 float4 / 64 lanes = 3
    float4 v = row4[i * 64 + lane];
    s += v.x * v.x + v.y * v.y + v.z * v.z + v.w * v.w;
  }
#pragma unroll
  for (int m = 32; m; m >>= 1) s += __shfl_xor(s, m);
  if (lane == 0) e2[code] = s;
}

// ---------------------------------------------------------------------------
// Kernel 1: fused distance GEMM + argmin.
// d(r,c) = e2[c] - 2 * dot(z_r, e_c)   (row-constant |z_r|^2 dropped; does not
// affect argmin). 256 threads: thread (ty,tx) = (tid>>4, tid&15) computes a
// 4-row x 8-code micro-tile. Rows are owned by one ty group -> no atomics.
// ---------------------------------------------------------------------------
__global__ __launch_bounds__(256, 2)
void dist_argmin(const float* __restrict__ z, const float* __restrict__ emb,
                 const float* __restrict__ e2, int* __restrict__ out_idx) {
  __shared__ float As[BK][BM + 4];   // +4 pad: staging writes 2-way (free)
  __shared__ float Bs[BK][BN + 4];

  const int tid = threadIdx.x;
  const int tx = tid & 15;           // code dim (16 threads x 8 codes = 128)
  const int ty = tid >> 4;           // row dim  (16 threads x 4 rows  = 64)
  const int rowBase = blockIdx.x * BM;

  // staging assignment: one float4 of A, two float4 of B per thread per K-tile
  const int a_row = tid >> 2;        // 0..63
  const int a_k   = (tid & 3) << 2;  // 0,4,8,12
  const int b_row0 = tid >> 2;       // 0..63
  const int b_row1 = b_row0 + 64;    // 64..127
  const int b_k   = a_k;

  const float* Aptr = z + (size_t)(rowBase + a_row) * D + a_k;

  float minval[4];
  int   minidx[4];
#pragma unroll
  for (int i = 0; i < 4; ++i) { minval[i] = INFINITY; minidx[i] = 0; }

  for (int ct = 0; ct < NE / BN; ++ct) {
    const float* Bbase = emb + (size_t)ct * BN * D + b_k;

    float acc[4][8];
#pragma unroll
    for (int i = 0; i < 4; ++i)
#pragma unroll
      for (int j = 0; j < 8; ++j) acc[i][j] = 0.f;

    // prefetch K-tile 0
    float4 pa  = *reinterpret_cast<const float4*>(Aptr);
    float4 pb0 = *reinterpret_cast<const float4*>(Bbase + (size_t)b_row0 * D);
    float4 pb1 = *reinterpret_cast<const float4*>(Bbase + (size_t)b_row1 * D);

    for (int kt = 0; kt < D / BK; ++kt) {
      __syncthreads();               // previous compute done reading LDS
      As[a_k + 0][a_row] = pa.x;
      As[a_k + 1][a_row] = pa.y;
      As[a_k + 2][a_row] = pa.z;
      As[a_k + 3][a_row] = pa.w;
      Bs[b_k + 0][b_row0] = pb0.x;
      Bs[b_k + 1][b_row0] = pb0.y;
      Bs[b_k + 2][b_row0] = pb0.z;
      Bs[b_k + 3][b_row0] = pb0.w;
      Bs[b_k + 0][b_row1] = pb1.x;
      Bs[b_k + 1][b_row1] = pb1.y;
      Bs[b_k + 2][b_row1] = pb1.z;
      Bs[b_k + 3][b_row1] = pb1.w;
      __syncthreads();
      if (kt + 1 < D / BK) {         // prefetch next K-tile; hides under compute
        const int ko = (kt + 1) * BK;
        pa  = *reinterpret_cast<const float4*>(Aptr + ko);
        pb0 = *reinterpret_cast<const float4*>(Bbase + (size_t)b_row0 * D + ko);
        pb1 = *reinterpret_cast<const float4*>(Bbase + (size_t)b_row1 * D + ko);
      }
#pragma unroll
      for (int k = 0; k < BK; ++k) {
        float a[4], b[8];
        *reinterpret_cast<float4*>(a)     = *reinterpret_cast<const float4*>(&As[k][ty * 4]);
        *reinterpret_cast<float4*>(b)     = *reinterpret_cast<const float4*>(&Bs[k][tx * 8]);
        *reinterpret_cast<float4*>(b + 4) = *reinterpret_cast<const float4*>(&Bs[k][tx * 8 + 4]);
#pragma unroll
        for (int i = 0; i < 4; ++i)
#pragma unroll
          for (int j = 0; j < 8; ++j) acc[i][j] = fmaf(a[i], b[j], acc[i][j]);
      }
    }

    // epilogue for this code tile: local 8-code min, then 16-lane butterfly
    float e2v[8];
    *reinterpret_cast<float4*>(e2v)     = *reinterpret_cast<const float4*>(&e2[ct * BN + tx * 8]);
    *reinterpret_cast<float4*>(e2v + 4) = *reinterpret_cast<const float4*>(&e2[ct * BN + tx * 8 + 4]);
#pragma unroll
    for (int i = 0; i < 4; ++i) {
      float bv = INFINITY;
      int   bi = 0;
#pragma unroll
      for (int j = 0; j < 8; ++j) {
        float dd = fmaf(-2.f, acc[i][j], e2v[j]);
        int   c  = ct * BN + tx * 8 + j;
        if (dd < bv) { bv = dd; bi = c; }   // strict <: first (lowest) idx wins
      }
#pragma unroll
      for (int m = 1; m < 16; m <<= 1) {    // tx lanes are stride-1 in the wave
        float ov = __shfl_xor(bv, m);
        int   oi = __shfl_xor(bi, m);
        if (ov < bv || (ov == bv && oi < bi)) { bv = ov; bi = oi; }
      }
      if (bv < minval[i] || (bv == minval[i] && bi < minidx[i])) {
        minval[i] = bv; minidx[i] = bi;
      }
    }
  }

  if (tx == 0) {
#pragma unroll
    for (int i = 0; i < 4; ++i) out_idx[rowBase + ty * 4 + i] = minidx[i];
  }
}

// ---------------------------------------------------------------------------
// Kernel 2: gather + rotation trick + loss. One wave per row.
// Given s2=e.e, t2=q.q, dz=e.q the whole transform is out_i = c_e*e_i + c_t*q_i.
// ---------------------------------------------------------------------------
__global__ __launch_bounds__(256)
void rotate_kernel(const float* __restrict__ z, const float* __restrict__ emb,
                   const int* __restrict__ idx, float* __restrict__ out,
                   float* __restrict__ loss_out) {
  const int wave = threadIdx.x >> 6;
  const int lane = threadIdx.x & 63;
  const int row = (blockIdx.x << 2) + wave;
  const float4* e4 = reinterpret_cast<const float4*>(z + (size_t)row * D);
  const int code = idx[row];
  const float4* t4 = reinterpret_cast<const float4*>(emb + (size_t)code * D);

  float4 ev[3], tv[3];
  float s2 = 0.f, t2 = 0.f, dz = 0.f;
#pragma unroll
  for (int i = 0; i < 3; ++i) {
    ev[i] = e4[i * 64 + lane];
    tv[i] = t4[i * 64 + lane];
    s2 += ev[i].x * ev[i].x + ev[i].y * ev[i].y + ev[i].z * ev[i].z + ev[i].w * ev[i].w;
    t2 += tv[i].x * tv[i].x + tv[i].y * tv[i].y + tv[i].z * tv[i].z + tv[i].w * tv[i].w;
    dz += ev[i].x * tv[i].x + ev[i].y * tv[i].y + ev[i].z * tv[i].z + ev[i].w * tv[i].w;
  }
#pragma unroll
  for (int m = 32; m; m >>= 1) {
    s2 += __shfl_xor(s2, m);
    t2 += __shfl_xor(t2, m);
    dz += __shfl_xor(dz, m);
  }

  const float ns  = sqrtf(s2);
  const float ntg = sqrtf(t2);
  const float rns = 1.f / fmaxf(ns, EPSV);
  const float rnt = 1.f / fmaxf(ntg, EPSV);
  // |u+q|^2 = |u|^2 + 2 u.q + |q|^2 with safe-divided u,q
  const float wn2 = s2 * rns * rns + 2.f * dz * rns * rnt + t2 * rnt * rnt;
  const float rnw = 1.f / fmaxf(sqrtf(wn2), EPSV);
  const float ew  = (s2 * rns + dz * rnt) * rnw;   // e . w
  const float eu  = s2 * rns;                      // e . u
  const float scale = ntg * rns;                   // norm_tgt / max(norm_src,eps)
  const float c_e = (1.f - 2.f * ew * rnw * rns) * scale;
  const float c_t = (2.f * eu * rnt - 2.f * ew * rnw * rnt) * scale;

  float4* o4 = reinterpret_cast<float4*>(out + (size_t)row * D);
#pragma unroll
  for (int i = 0; i < 3; ++i) {
    float4 o;
    o.x = c_e * ev[i].x + c_t * tv[i].x;
    o.y = c_e * ev[i].y + c_t * tv[i].y;
    o.z = c_e * ev[i].z + c_t * tv[i].z;
    o.w = c_e * ev[i].w + c_t * tv[i].w;
    o4[i * 64 + lane] = o;
  }

  if (lane == 0) {
    // per-row sum of (zq - z)^2 = s2 + t2 - 2 dz ; loss = 2*mean
    const float rowloss = (s2 + t2 - 2.f * dz) * (2.f / (float)((size_t)NR * D));
    atomicAdd(loss_out, rowloss);
  }
}

// ---------------------------------------------------------------------------
extern "C" void kernel_launch(void* const* d_in, const int* in_sizes, int n_in,
                              void* d_out, int out_size, void* d_ws, size_t ws_size,
                              hipStream_t stream) {
  const float* z   = (const float*)d_in[0];   // [32768, 768]
  const float* emb = (const float*)d_in[1];   // [8192, 768]
  float* out  = (float*)d_out;                // [32768*768] rotated + [1] loss
  float* loss = out + (size_t)NR * D;

  int*   idx = (int*)d_ws;                          // 32768 ints
  float* e2  = (float*)((char*)d_ws + NR * sizeof(int));  // 8192 floats

  hipMemsetAsync(loss, 0, sizeof(float), stream);   // capture-legal
  e2_kernel<<<NE / 4, 256, 0, stream>>>(emb, e2);
  dist_argmin<<<NR / BM, 256, 0, stream>>>(z, emb, e2, idx);
  rotate_kernel<<<NR / 4, 256, 0, stream>>>(z, emb, idx, out, loss);
}

// Round 4
// 3115.062 us; speedup vs baseline: 2.2376x; 2.2376x over previous
//
#include <hip/hip_runtime.h>
#include <hip/hip_bf16.h>

typedef unsigned long long u64;
typedef unsigned short ushort_t;
typedef __attribute__((ext_vector_type(8))) short short8;
typedef __attribute__((ext_vector_type(4))) float f32x4;

constexpr int D  = 768;
constexpr int NE = 8192;
constexpr int NR = 32768;
constexpr float EPSV = 1e-6f;
constexpr float EPSM = 0.05f;   // margin for exact-rescan flagging (~25x err bound)
constexpr int NCT = NE / 128;   // 64 code tiles
constexpr int NKT = D / 32;     // 24 k tiles

// ---------------- packed (distance, index) helpers ----------------
__device__ __forceinline__ u64 packdi(float d, int code) {
  unsigned u = __float_as_uint(d);
  u = (u & 0x80000000u) ? ~u : (u | 0x80000000u);
  return ((u64)u << 32) | (unsigned)code;
}
__device__ __forceinline__ float unpackd(u64 p) {
  unsigned u = (unsigned)(p >> 32);
  unsigned bits = (u & 0x80000000u) ? (u & 0x7fffffffu) : ~u;
  return __uint_as_float(bits);
}
__device__ __forceinline__ u64 umin64(u64 a, u64 b) { return a < b ? a : b; }
__device__ __forceinline__ u64 umax64(u64 a, u64 b) { return a < b ? b : a; }

// ---------------- async global->LDS (16B per lane) ----------------
__device__ __forceinline__ void gl16(const void* g, void* l) {
  __builtin_amdgcn_global_load_lds(
      (const __attribute__((address_space(1))) int*)g,
      (__attribute__((address_space(3))) int*)l, 16, 0, 0);
}

// ---------------------------------------------------------------------------
// split f32 -> bf16 hi + bf16 lo (RN-even both), 4 elems/thread
// ---------------------------------------------------------------------------
__global__ __launch_bounds__(256) void split_bf16(const float* __restrict__ x,
                                                  ushort_t* __restrict__ hi,
                                                  ushort_t* __restrict__ lo, int n4) {
  int i = blockIdx.x * 256 + threadIdx.x;
  if (i >= n4) return;
  float4 v = reinterpret_cast<const float4*>(x)[i];
  float f[4] = {v.x, v.y, v.z, v.w};
  ushort_t hh[4], ll[4];
#pragma unroll
  for (int j = 0; j < 4; ++j) {
    unsigned u = __float_as_uint(f[j]);
    unsigned hb = (u + 0x7fffu + ((u >> 16) & 1u)) >> 16;
    float hf = __uint_as_float(hb << 16);
    float lf = f[j] - hf;
    unsigned ul = __float_as_uint(lf);
    unsigned lb = (ul + 0x7fffu + ((ul >> 16) & 1u)) >> 16;
    hh[j] = (ushort_t)hb; ll[j] = (ushort_t)lb;
  }
  reinterpret_cast<ushort4*>(hi)[i] = make_ushort4(hh[0], hh[1], hh[2], hh[3]);
  reinterpret_cast<ushort4*>(lo)[i] = make_ushort4(ll[0], ll[1], ll[2], ll[3]);
}

// ---------------------------------------------------------------------------
// per-code squared norms (f32)
// ---------------------------------------------------------------------------
__global__ __launch_bounds__(256) void e2_kernel(const float* __restrict__ emb,
                                                 float* __restrict__ e2) {
  const int wave = threadIdx.x >> 6, lane = threadIdx.x & 63;
  const int code = (blockIdx.x << 2) + wave;
  const float4* row4 = reinterpret_cast<const float4*>(emb + (size_t)code * D);
  float s = 0.f;
#pragma unroll
  for (int i = 0; i < 3; ++i) {
    float4 v = row4[i * 64 + lane];
    s += v.x * v.x + v.y * v.y + v.z * v.z + v.w * v.w;
  }
#pragma unroll
  for (int m = 32; m; m >>= 1) s += __shfl_xor(s, m);
  if (lane == 0) e2[code] = s;
}

// ---------------------------------------------------------------------------
// MFMA distance GEMM + per-row top-2 per 128-code tile.
// dot = zh*eh + zh*el + zl*eh  (3-product split-bf16).  d = e2[c] - 2*dot.
// 128x128 tile, 4 waves (2x2), BK=32, double-buffered LDS via global_load_lds.
// ---------------------------------------------------------------------------
__global__ __launch_bounds__(256, 2)
void mfma_dist(const ushort_t* __restrict__ zh, const ushort_t* __restrict__ zl,
               const ushort_t* __restrict__ eh, const ushort_t* __restrict__ el,
               const float* __restrict__ e2g, u64* __restrict__ part) {
  __shared__ __align__(16) ushort_t Lb[2][4][4096];   // [buf][Ah,Al,Bh,Bl][128*32]

  const int tid  = threadIdx.x;
  const int wave = tid >> 6, lane = tid & 63;
  const int rt = blockIdx.x >> 6;          // 256 row tiles
  const int ct = blockIdx.x & 63;          // 64 code tiles (fastest -> L2 reuse of A)
  const int rowBase = rt * 128, codeBase = ct * 128;
  const int wr = (wave >> 1) * 64;         // wave row offset {0,64}
  const int wc = (wave & 1) * 64;          // wave col offset {0,64}
  const int r = lane & 15, s = lane >> 4;

  // staging mapping: 512 16B-segments; thread t covers seg t and t+256.
  const int idx0 = tid, idx1 = tid + 256;
  const int rA0 = idx0 >> 2, sg0 = idx0 & 3;
  const int rA1 = idx1 >> 2, sg1 = idx1 & 3;
  const size_t gA0 = (size_t)(rowBase + rA0) * D + sg0 * 8;
  const size_t gA1 = (size_t)(rowBase + rA1) * D + sg1 * 8;
  const size_t gB0 = (size_t)(codeBase + rA0) * D + sg0 * 8;
  const size_t gB1 = (size_t)(codeBase + rA1) * D + sg1 * 8;
  const int l0 = idx0 * 8, l1 = idx1 * 8;  // LDS ushort offsets (linear, lane*16B)

#define STAGE(b, k0) do {                                          \
    gl16(zh + gA0 + (k0), &Lb[b][0][l0]);                          \
    gl16(zh + gA1 + (k0), &Lb[b][0][l1]);                          \
    gl16(zl + gA0 + (k0), &Lb[b][1][l0]);                          \
    gl16(zl + gA1 + (k0), &Lb[b][1][l1]);                          \
    gl16(eh + gB0 + (k0), &Lb[b][2][l0]);                          \
    gl16(eh + gB1 + (k0), &Lb[b][2][l1]);                          \
    gl16(el + gB0 + (k0), &Lb[b][3][l0]);                          \
    gl16(el + gB1 + (k0), &Lb[b][3][l1]);                          \
  } while (0)

  f32x4 acc[4][4];
#pragma unroll
  for (int m = 0; m < 4; ++m)
#pragma unroll
    for (int n = 0; n < 4; ++n) acc[m][n] = (f32x4){0.f, 0.f, 0.f, 0.f};

  const int aoff = (wr + r) * 32 + s * 8;  // fragment base (ushort units)
  const int boff = (wc + r) * 32 + s * 8;

  int buf = 0;
  STAGE(0, 0);
  __syncthreads();

  for (int kt = 0; kt < NKT; ++kt) {
    if (kt + 1 < NKT) STAGE(buf ^ 1, (kt + 1) * 32);

    short8 ah[4], al[4], bh[4], bl[4];
#pragma unroll
    for (int m = 0; m < 4; ++m) {
      ah[m] = *(const short8*)&Lb[buf][0][aoff + m * 512];
      al[m] = *(const short8*)&Lb[buf][1][aoff + m * 512];
    }
#pragma unroll
    for (int n = 0; n < 4; ++n) {
      bh[n] = *(const short8*)&Lb[buf][2][boff + n * 512];
      bl[n] = *(const short8*)&Lb[buf][3][boff + n * 512];
    }
#pragma unroll
    for (int m = 0; m < 4; ++m)
#pragma unroll
      for (int n = 0; n < 4; ++n) {
        acc[m][n] = __builtin_amdgcn_mfma_f32_16x16x32_bf16(ah[m], bh[n], acc[m][n], 0, 0, 0);
        acc[m][n] = __builtin_amdgcn_mfma_f32_16x16x32_bf16(ah[m], bl[n], acc[m][n], 0, 0, 0);
        acc[m][n] = __builtin_amdgcn_mfma_f32_16x16x32_bf16(al[m], bh[n], acc[m][n], 0, 0, 0);
      }
    __syncthreads();
    buf ^= 1;
  }
#undef STAGE

  // ---- epilogue: d = e2 - 2*dot ; per-row top2 over this 128-code tile ----
  float e2v[4];
#pragma unroll
  for (int n = 0; n < 4; ++n) e2v[n] = e2g[codeBase + wc + n * 16 + r];

  u64* sm2 = (u64*)&Lb[0][0][0];           // reuse LDS: [2][128][2] u64 = 4KB
  const int wcIdx = wave & 1;

#pragma unroll
  for (int m = 0; m < 4; ++m) {
#pragma unroll
    for (int j = 0; j < 4; ++j) {
      u64 p1 = ~0ull, p2 = ~0ull;
#pragma unroll
      for (int n = 0; n < 4; ++n) {
        float d = fmaf(-2.f, acc[m][n][j], e2v[n]);
        u64 c = packdi(d, codeBase + wc + n * 16 + r);
        if (c < p1) { p2 = p1; p1 = c; } else if (c < p2) { p2 = c; }
      }
#pragma unroll
      for (int mm = 1; mm < 16; mm <<= 1) {
        u64 o1 = __shfl_xor(p1, mm);
        u64 o2 = __shfl_xor(p2, mm);
        u64 lo = umin64(p1, o1), hi = umax64(p1, o1);
        p1 = lo; p2 = umin64(hi, umin64(p2, o2));
      }
      if (r == 0) {
        int rowl = wr + m * 16 + s * 4 + j;
        sm2[(wcIdx * 128 + rowl) * 2 + 0] = p1;
        sm2[(wcIdx * 128 + rowl) * 2 + 1] = p2;
      }
    }
  }
  __syncthreads();
  if (tid < 128) {
    u64 a1 = sm2[tid * 2], a2 = sm2[tid * 2 + 1];
    u64 b1 = sm2[(128 + tid) * 2], b2 = sm2[(128 + tid) * 2 + 1];
    u64 m1 = umin64(a1, b1);
    u64 m2 = umin64(umax64(a1, b1), umin64(a2, b2));
    size_t base = ((size_t)(rowBase + tid) << 7) + ct * 2;
    part[base] = m1;
    part[base + 1] = m2;
  }
}

// ---------------------------------------------------------------------------
// merge per-tile top2 -> global top2 per row. Deterministic, atomic-free:
// writes idx/flags/rmin for EVERY row unconditionally.
// ---------------------------------------------------------------------------
__global__ __launch_bounds__(256)
void merge_rows(const u64* __restrict__ part, int* __restrict__ idx,
                int* __restrict__ flags, u64* __restrict__ rmin) {
  const int row = blockIdx.x * 4 + (threadIdx.x >> 6);
  const int lane = threadIdx.x & 63;
  const u64* p = part + ((size_t)row << 7);
  u64 a = p[lane], b = p[lane + 64];
  u64 p1 = umin64(a, b), p2 = umax64(a, b);
#pragma unroll
  for (int mm = 1; mm < 64; mm <<= 1) {
    u64 o1 = __shfl_xor(p1, mm);
    u64 o2 = __shfl_xor(p2, mm);
    u64 lo = umin64(p1, o1), hi = umax64(p1, o1);
    p1 = lo; p2 = umin64(hi, umin64(p2, o2));
  }
  if (lane == 0) {
    idx[row] = (int)(p1 & 0xffffffffu);
    flags[row] = (unpackd(p2) - unpackd(p1) <= EPSM) ? 1 : 0;
    rmin[row] = ~0ull;
  }
}

// ---------------------------------------------------------------------------
// exact f32 rescan for flagged rows. Grid-stride over NR*4 units
// (row, 2048-code chunk); uniform skip of unflagged rows.
// ---------------------------------------------------------------------------
__global__ __launch_bounds__(256)
void rescue(const float* __restrict__ z, const float* __restrict__ emb,
            const float* __restrict__ e2, const int* __restrict__ flags,
            u64* __restrict__ rmin) {
  __shared__ float zr[D];
  __shared__ u64 red[4];
  const int tid = threadIdx.x, wave = tid >> 6, lane = tid & 63;
  for (int u = blockIdx.x; u < NR * 4; u += gridDim.x) {
    const int row = u >> 2;
    if (!flags[row]) continue;               // block-uniform
    const int cb = (u & 3) << 11;            // 2048 codes per chunk
    for (int i = tid; i < D / 4; i += 256)
      ((float4*)zr)[i] = ((const float4*)(z + (size_t)row * D))[i];
    __syncthreads();
    u64 best = ~0ull;
#pragma unroll
    for (int cc = 0; cc < 8; ++cc) {
      const int code = cb + cc * 256 + tid;
      const float4* e4 = (const float4*)(emb + (size_t)code * D);
      float dot = 0.f;
#pragma unroll 8
      for (int i = 0; i < D / 4; ++i) {
        float4 ev = e4[i]; float4 zv = ((const float4*)zr)[i];
        dot = fmaf(ev.x, zv.x, dot); dot = fmaf(ev.y, zv.y, dot);
        dot = fmaf(ev.z, zv.z, dot); dot = fmaf(ev.w, zv.w, dot);
      }
      float d = e2[code] - 2.f * dot;
      best = umin64(best, packdi(d, code));
    }
#pragma unroll
    for (int mm = 1; mm < 64; mm <<= 1) best = umin64(best, __shfl_xor(best, mm));
    if (lane == 0) red[wave] = best;
    __syncthreads();
    if (tid == 0) {
      best = umin64(umin64(red[0], red[1]), umin64(red[2], red[3]));
      atomicMin(&rmin[row], best);
    }
    __syncthreads();
  }
}

__global__ __launch_bounds__(256)
void fixup(const int* __restrict__ flags, const u64* __restrict__ rmin,
           int* __restrict__ idx) {
  const int row = blockIdx.x * 256 + threadIdx.x;
  if (row < NR && flags[row]) idx[row] = (int)(rmin[row] & 0xffffffffu);
}

// ---------------------------------------------------------------------------
// fallback f32 distance+argmin (round-1 kernel, used only if ws too small)
// ---------------------------------------------------------------------------
__global__ __launch_bounds__(256, 2)
void dist_argmin(const float* __restrict__ z, const float* __restrict__ emb,
                 const float* __restrict__ e2, int* __restrict__ out_idx) {
  __shared__ float As[16][68];
  __shared__ float Bs[16][132];
  const int tid = threadIdx.x;
  const int tx = tid & 15, ty = tid >> 4;
  const int rowBase = blockIdx.x * 64;
  const int a_row = tid >> 2, a_k = (tid & 3) << 2;
  const int b_row0 = tid >> 2, b_row1 = b_row0 + 64, b_k = a_k;
  const float* Aptr = z + (size_t)(rowBase + a_row) * D + a_k;
  float minval[4]; int minidx[4];
#pragma unroll
  for (int i = 0; i < 4; ++i) { minval[i] = INFINITY; minidx[i] = 0; }
  for (int ctile = 0; ctile < NE / 128; ++ctile) {
    const float* Bbase = emb + (size_t)ctile * 128 * D + b_k;
    float acc[4][8];
#pragma unroll
    for (int i = 0; i < 4; ++i)
#pragma unroll
      for (int j = 0; j < 8; ++j) acc[i][j] = 0.f;
    float4 pa = *reinterpret_cast<const float4*>(Aptr);
    float4 pb0 = *reinterpret_cast<const float4*>(Bbase + (size_t)b_row0 * D);
    float4 pb1 = *reinterpret_cast<const float4*>(Bbase + (size_t)b_row1 * D);
    for (int kt = 0; kt < D / 16; ++kt) {
      __syncthreads();
      As[a_k][a_row] = pa.x; As[a_k + 1][a_row] = pa.y;
      As[a_k + 2][a_row] = pa.z; As[a_k + 3][a_row] = pa.w;
      Bs[b_k][b_row0] = pb0.x; Bs[b_k + 1][b_row0] = pb0.y;
      Bs[b_k + 2][b_row0] = pb0.z; Bs[b_k + 3][b_row0] = pb0.w;
      Bs[b_k][b_row1] = pb1.x; Bs[b_k + 1][b_row1] = pb1.y;
      Bs[b_k + 2][b_row1] = pb1.z; Bs[b_k + 3][b_row1] = pb1.w;
      __syncthreads();
      if (kt + 1 < D / 16) {
        const int ko = (kt + 1) * 16;
        pa = *reinterpret_cast<const float4*>(Aptr + ko);
        pb0 = *reinterpret_cast<const float4*>(Bbase + (size_t)b_row0 * D + ko);
        pb1 = *reinterpret_cast<const float4*>(Bbase + (size_t)b_row1 * D + ko);
      }
#pragma unroll
      for (int k = 0; k < 16; ++k) {
        float a[4], b[8];
        *reinterpret_cast<float4*>(a) = *reinterpret_cast<const float4*>(&As[k][ty * 4]);
        *reinterpret_cast<float4*>(b) = *reinterpret_cast<const float4*>(&Bs[k][tx * 8]);
        *reinterpret_cast<float4*>(b + 4) = *reinterpret_cast<const float4*>(&Bs[k][tx * 8 + 4]);
#pragma unroll
        for (int i = 0; i < 4; ++i)
#pragma unroll
          for (int j = 0; j < 8; ++j) acc[i][j] = fmaf(a[i], b[j], acc[i][j]);
      }
    }
    float e2v[8];
    *reinterpret_cast<float4*>(e2v) = *reinterpret_cast<const float4*>(&e2[ctile * 128 + tx * 8]);
    *reinterpret_cast<float4*>(e2v + 4) = *reinterpret_cast<const float4*>(&e2[ctile * 128 + tx * 8 + 4]);
#pragma unroll
    for (int i = 0; i < 4; ++i) {
      float bv = INFINITY; int bi = 0;
#pragma unroll
      for (int j = 0; j < 8; ++j) {
        float dd = fmaf(-2.f, acc[i][j], e2v[j]);
        int c = ctile * 128 + tx * 8 + j;
        if (dd < bv) { bv = dd; bi = c; }
      }
#pragma unroll
      for (int m = 1; m < 16; m <<= 1) {
        float ov = __shfl_xor(bv, m); int oi = __shfl_xor(bi, m);
        if (ov < bv || (ov == bv && oi < bi)) { bv = ov; bi = oi; }
      }
      if (bv < minval[i] || (bv == minval[i] && bi < minidx[i])) {
        minval[i] = bv; minidx[i] = bi;
      }
    }
  }
  if (tx == 0) {
#pragma unroll
    for (int i = 0; i < 4; ++i) out_idx[rowBase + ty * 4 + i] = minidx[i];
  }
}

// ---------------------------------------------------------------------------
// gather + rotation trick + loss (closed form per row)
// ---------------------------------------------------------------------------
__global__ __launch_bounds__(256)
void rotate_kernel(const float* __restrict__ z, const float* __restrict__ emb,
                   const int* __restrict__ idx, float* __restrict__ out,
                   float* __restrict__ loss_out) {
  const int wave = threadIdx.x >> 6, lane = threadIdx.x & 63;
  const int row = (blockIdx.x << 2) + wave;
  const float4* e4 = reinterpret_cast<const float4*>(z + (size_t)row * D);
  const int code = idx[row];
  const float4* t4 = reinterpret_cast<const float4*>(emb + (size_t)code * D);
  float4 ev[3], tv[3];
  float s2 = 0.f, t2 = 0.f, dz = 0.f;
#pragma unroll
  for (int i = 0; i < 3; ++i) {
    ev[i] = e4[i * 64 + lane];
    tv[i] = t4[i * 64 + lane];
    s2 += ev[i].x * ev[i].x + ev[i].y * ev[i].y + ev[i].z * ev[i].z + ev[i].w * ev[i].w;
    t2 += tv[i].x * tv[i].x + tv[i].y * tv[i].y + tv[i].z * tv[i].z + tv[i].w * tv[i].w;
    dz += ev[i].x * tv[i].x + ev[i].y * tv[i].y + ev[i].z * tv[i].z + ev[i].w * tv[i].w;
  }
#pragma unroll
  for (int m = 32; m; m >>= 1) {
    s2 += __shfl_xor(s2, m); t2 += __shfl_xor(t2, m); dz += __shfl_xor(dz, m);
  }
  const float ns = sqrtf(s2), ntg = sqrtf(t2);
  const float rns = 1.f / fmaxf(ns, EPSV);
  const float rnt = 1.f / fmaxf(ntg, EPSV);
  const float wn2 = s2 * rns * rns + 2.f * dz * rns * rnt + t2 * rnt * rnt;
  const float rnw = 1.f / fmaxf(sqrtf(wn2), EPSV);
  const float ew = (s2 * rns + dz * rnt) * rnw;
  const float eu = s2 * rns;
  const float scale = ntg * rns;
  const float c_e = (1.f - 2.f * ew * rnw * rns) * scale;
  const float c_t = (2.f * eu * rnt - 2.f * ew * rnw * rnt) * scale;
  float4* o4 = reinterpret_cast<float4*>(out + (size_t)row * D);
#pragma unroll
  for (int i = 0; i < 3; ++i) {
    float4 o;
    o.x = c_e * ev[i].x + c_t * tv[i].x;
    o.y = c_e * ev[i].y + c_t * tv[i].y;
    o.z = c_e * ev[i].z + c_t * tv[i].z;
    o.w = c_e * ev[i].w + c_t * tv[i].w;
    o4[i * 64 + lane] = o;
  }
  if (lane == 0) {
    const float rowloss = (s2 + t2 - 2.f * dz) * (2.f / (float)((size_t)NR * D));
    atomicAdd(loss_out, rowloss);
  }
}

// ---------------------------------------------------------------------------
extern "C" void kernel_launch(void* const* d_in, const int* in_sizes, int n_in,
                              void* d_out, int out_size, void* d_ws, size_t ws_size,
                              hipStream_t stream) {
  const float* z   = (const float*)d_in[0];
  const float* emb = (const float*)d_in[1];
  float* out  = (float*)d_out;
  float* loss = out + (size_t)NR * D;

  // ws layout
  char* w = (char*)d_ws;
  const size_t SZ_ZH = (size_t)NR * D * 2;
  const size_t SZ_EH = (size_t)NE * D * 2;
  const size_t SZ_PART = (size_t)NR * NCT * 2 * 8;
  ushort_t* zh = (ushort_t*)w;              w += SZ_ZH;
  ushort_t* zl = (ushort_t*)w;              w += SZ_ZH;
  ushort_t* eh = (ushort_t*)w;              w += SZ_EH;
  ushort_t* el = (ushort_t*)w;              w += SZ_EH;
  u64* part = (u64*)w;                      w += SZ_PART;
  float* e2 = (float*)w;                    w += (size_t)NE * 4;
  int* idx = (int*)w;                       w += (size_t)NR * 4;
  int* flags = (int*)w;                     w += (size_t)NR * 4;
  u64* rmin = (u64*)w;                      w += (size_t)NR * 8;
  const size_t REQ = (size_t)(w - (char*)d_ws);

  hipMemsetAsync(loss, 0, sizeof(float), stream);

  if (ws_size >= REQ) {
    hipMemsetAsync(rmin, 0xFF, (size_t)NR * 8, stream);   // belt & braces
    split_bf16<<<(NR * D / 4 + 255) / 256, 256, 0, stream>>>(z, zh, zl, NR * D / 4);
    split_bf16<<<(NE * D / 4 + 255) / 256, 256, 0, stream>>>(emb, eh, el, NE * D / 4);
    e2_kernel<<<NE / 4, 256, 0, stream>>>(emb, e2);
    mfma_dist<<<(NR / 128) * NCT, 256, 0, stream>>>(zh, zl, eh, el, e2, part);
    merge_rows<<<NR / 4, 256, 0, stream>>>(part, idx, flags, rmin);
    rescue<<<4096, 256, 0, stream>>>(z, emb, e2, flags, rmin);
    fixup<<<NR / 256, 256, 0, stream>>>(flags, rmin, idx);
  } else {
    // fallback: f32 vector path (fits in tiny ws)
    int* fidx = (int*)d_ws;
    float* fe2 = (float*)((char*)d_ws + (size_t)NR * 4);
    e2_kernel<<<NE / 4, 256, 0, stream>>>(emb, fe2);
    dist_argmin<<<NR / 64, 256, 0, stream>>>(z, emb, fe2, fidx);
    rotate_kernel<<<NR / 4, 256, 0, stream>>>(z, emb, fidx, out, loss);
    return;
  }
  rotate_kernel<<<NR / 4, 256, 0, stream>>>(z, emb, idx, out, loss);
}

// Round 9
// 2248.926 us; speedup vs baseline: 3.0994x; 1.3851x over previous
//
#include <hip/hip_runtime.h>
#include <hip/hip_bf16.h>

typedef unsigned long long u64;
typedef unsigned short ushort_t;
typedef __attribute__((ext_vector_type(8))) short short8;
typedef __attribute__((ext_vector_type(4))) float f32x4;

constexpr int D  = 768;
constexpr int NE = 8192;
constexpr int NR = 32768;
constexpr float EPSV = 1e-6f;
constexpr float EPSM = 0.05f;   // margin for exact-rescan flagging (~50x err bound)
constexpr int NCT = NE / 128;   // 64 code tiles
constexpr int NKT = D / 32;     // 24 k tiles

// ---------------- packed (distance, index) helpers ----------------
__device__ __forceinline__ u64 packdi(float d, int code) {
  unsigned u = __float_as_uint(d);
  u = (u & 0x80000000u) ? ~u : (u | 0x80000000u);
  return ((u64)u << 32) | (unsigned)code;
}
__device__ __forceinline__ float unpackd(u64 p) {
  unsigned u = (unsigned)(p >> 32);
  unsigned bits = (u & 0x80000000u) ? (u & 0x7fffffffu) : ~u;
  return __uint_as_float(bits);
}
__device__ __forceinline__ u64 umin64(u64 a, u64 b) { return a < b ? a : b; }
__device__ __forceinline__ u64 umax64(u64 a, u64 b) { return a < b ? b : a; }

// ---------------- async global->LDS (16B per lane) ----------------
__device__ __forceinline__ void gl16(const void* g, void* l) {
  __builtin_amdgcn_global_load_lds(
      (const __attribute__((address_space(1))) int*)g,
      (__attribute__((address_space(3))) int*)l, 16, 0, 0);
}

// ---------------------------------------------------------------------------
// split f32 -> bf16 hi + bf16 lo (RN-even both), 4 elems/thread
// ---------------------------------------------------------------------------
__global__ __launch_bounds__(256) void split_bf16(const float* __restrict__ x,
                                                  ushort_t* __restrict__ hi,
                                                  ushort_t* __restrict__ lo, int n4) {
  int i = blockIdx.x * 256 + threadIdx.x;
  if (i >= n4) return;
  float4 v = reinterpret_cast<const float4*>(x)[i];
  float f[4] = {v.x, v.y, v.z, v.w};
  ushort_t hh[4], ll[4];
#pragma unroll
  for (int j = 0; j < 4; ++j) {
    unsigned u = __float_as_uint(f[j]);
    unsigned hb = (u + 0x7fffu + ((u >> 16) & 1u)) >> 16;
    float hf = __uint_as_float(hb << 16);
    float lf = f[j] - hf;
    unsigned ul = __float_as_uint(lf);
    unsigned lb = (ul + 0x7fffu + ((ul >> 16) & 1u)) >> 16;
    hh[j] = (ushort_t)hb; ll[j] = (ushort_t)lb;
  }
  reinterpret_cast<ushort4*>(hi)[i] = make_ushort4(hh[0], hh[1], hh[2], hh[3]);
  reinterpret_cast<ushort4*>(lo)[i] = make_ushort4(ll[0], ll[1], ll[2], ll[3]);
}

// ---------------------------------------------------------------------------
// per-code squared norms (f32)
// ---------------------------------------------------------------------------
__global__ __launch_bounds__(256) void e2_kernel(const float* __restrict__ emb,
                                                 float* __restrict__ e2) {
  const int wave = threadIdx.x >> 6, lane = threadIdx.x & 63;
  const int code = (blockIdx.x << 2) + wave;
  const float4* row4 = reinterpret_cast<const float4*>(emb + (size_t)code * D);
  float s = 0.f;
#pragma unroll
  for (int i = 0; i < 3; ++i) {
    float4 v = row4[i * 64 + lane];
    s += v.x * v.x + v.y * v.y + v.z * v.z + v.w * v.w;
  }
#pragma unroll
  for (int m = 32; m; m >>= 1) s += __shfl_xor(s, m);
  if (lane == 0) e2[code] = s;
}

// ---------------------------------------------------------------------------
// MFMA distance GEMM + per-row top-2 per 128-code tile.
// dot = zh*eh + zh*el + zl*eh  (3-product split-bf16).  d = e2[c] - 2*dot.
// 128x128 tile, 4 waves (2x2), BK=32, double-buffered LDS via global_load_lds.
// ---------------------------------------------------------------------------
__global__ __launch_bounds__(256, 2)
void mfma_dist(const ushort_t* __restrict__ zh, const ushort_t* __restrict__ zl,
               const ushort_t* __restrict__ eh, const ushort_t* __restrict__ el,
               const float* __restrict__ e2g, u64* __restrict__ part) {
  __shared__ __align__(16) ushort_t Lb[2][4][4096];   // [buf][Ah,Al,Bh,Bl][128*32]

  const int tid  = threadIdx.x;
  const int wave = tid >> 6, lane = tid & 63;
  const int rt = blockIdx.x >> 6;          // 256 row tiles
  const int ct = blockIdx.x & 63;          // 64 code tiles (fastest -> L2 reuse of A)
  const int rowBase = rt * 128, codeBase = ct * 128;
  const int wr = (wave >> 1) * 64;         // wave row offset {0,64}
  const int wc = (wave & 1) * 64;          // wave col offset {0,64}
  const int r = lane & 15, s = lane >> 4;

  // staging mapping: 512 16B-segments; thread t covers seg t and t+256.
  const int idx0 = tid, idx1 = tid + 256;
  const int rA0 = idx0 >> 2, sg0 = idx0 & 3;
  const int rA1 = idx1 >> 2, sg1 = idx1 & 3;
  const size_t gA0 = (size_t)(rowBase + rA0) * D + sg0 * 8;
  const size_t gA1 = (size_t)(rowBase + rA1) * D + sg1 * 8;
  const size_t gB0 = (size_t)(codeBase + rA0) * D + sg0 * 8;
  const size_t gB1 = (size_t)(codeBase + rA1) * D + sg1 * 8;
  const int l0 = idx0 * 8, l1 = idx1 * 8;  // LDS ushort offsets (linear, lane*16B)

#define STAGE(b, k0) do {                                          \
    gl16(zh + gA0 + (k0), &Lb[b][0][l0]);                          \
    gl16(zh + gA1 + (k0), &Lb[b][0][l1]);                          \
    gl16(zl + gA0 + (k0), &Lb[b][1][l0]);                          \
    gl16(zl + gA1 + (k0), &Lb[b][1][l1]);                          \
    gl16(eh + gB0 + (k0), &Lb[b][2][l0]);                          \
    gl16(eh + gB1 + (k0), &Lb[b][2][l1]);                          \
    gl16(el + gB0 + (k0), &Lb[b][3][l0]);                          \
    gl16(el + gB1 + (k0), &Lb[b][3][l1]);                          \
  } while (0)

  f32x4 acc[4][4];
#pragma unroll
  for (int m = 0; m < 4; ++m)
#pragma unroll
    for (int n = 0; n < 4; ++n) acc[m][n] = (f32x4){0.f, 0.f, 0.f, 0.f};

  const int aoff = (wr + r) * 32 + s * 8;  // fragment base (ushort units)
  const int boff = (wc + r) * 32 + s * 8;

  int buf = 0;
  STAGE(0, 0);
  __syncthreads();

  for (int kt = 0; kt < NKT; ++kt) {
    if (kt + 1 < NKT) STAGE(buf ^ 1, (kt + 1) * 32);

    short8 ah[4], al[4], bh[4], bl[4];
#pragma unroll
    for (int m = 0; m < 4; ++m) {
      ah[m] = *(const short8*)&Lb[buf][0][aoff + m * 512];
      al[m] = *(const short8*)&Lb[buf][1][aoff + m * 512];
    }
#pragma unroll
    for (int n = 0; n < 4; ++n) {
      bh[n] = *(const short8*)&Lb[buf][2][boff + n * 512];
      bl[n] = *(const short8*)&Lb[buf][3][boff + n * 512];
    }
#pragma unroll
    for (int m = 0; m < 4; ++m)
#pragma unroll
      for (int n = 0; n < 4; ++n) {
        acc[m][n] = __builtin_amdgcn_mfma_f32_16x16x32_bf16(ah[m], bh[n], acc[m][n], 0, 0, 0);
        acc[m][n] = __builtin_amdgcn_mfma_f32_16x16x32_bf16(ah[m], bl[n], acc[m][n], 0, 0, 0);
        acc[m][n] = __builtin_amdgcn_mfma_f32_16x16x32_bf16(al[m], bh[n], acc[m][n], 0, 0, 0);
      }
    __syncthreads();
    buf ^= 1;
  }
#undef STAGE

  // ---- epilogue: d = e2 - 2*dot ; per-row top2 over this 128-code tile ----
  float e2v[4];
#pragma unroll
  for (int n = 0; n < 4; ++n) e2v[n] = e2g[codeBase + wc + n * 16 + r];

  u64* sm2 = (u64*)&Lb[0][0][0];           // reuse LDS: [2][128][2] u64 = 4KB
  const int wcIdx = wave & 1;

#pragma unroll
  for (int m = 0; m < 4; ++m) {
#pragma unroll
    for (int j = 0; j < 4; ++j) {
      u64 p1 = ~0ull, p2 = ~0ull;
#pragma unroll
      for (int n = 0; n < 4; ++n) {
        float d = fmaf(-2.f, acc[m][n][j], e2v[n]);
        u64 c = packdi(d, codeBase + wc + n * 16 + r);
        if (c < p1) { p2 = p1; p1 = c; } else if (c < p2) { p2 = c; }
      }
#pragma unroll
      for (int mm = 1; mm < 16; mm <<= 1) {
        u64 o1 = __shfl_xor(p1, mm);
        u64 o2 = __shfl_xor(p2, mm);
        u64 lo = umin64(p1, o1), hi = umax64(p1, o1);
        p1 = lo; p2 = umin64(hi, umin64(p2, o2));
      }
      if (r == 0) {
        int rowl = wr + m * 16 + s * 4 + j;
        sm2[(wcIdx * 128 + rowl) * 2 + 0] = p1;
        sm2[(wcIdx * 128 + rowl) * 2 + 1] = p2;
      }
    }
  }
  __syncthreads();
  if (tid < 128) {
    u64 a1 = sm2[tid * 2], a2 = sm2[tid * 2 + 1];
    u64 b1 = sm2[(128 + tid) * 2], b2 = sm2[(128 + tid) * 2 + 1];
    u64 m1 = umin64(a1, b1);
    u64 m2 = umin64(umax64(a1, b1), umin64(a2, b2));
    size_t base = ((size_t)(rowBase + tid) << 7) + ct * 2;
    part[base] = m1;
    part[base + 1] = m2;
  }
}

// ---------------------------------------------------------------------------
// merge per-tile top2 -> global top2 per row. Deterministic, atomic-free:
// writes idx/flags/rmin for EVERY row unconditionally.
// ---------------------------------------------------------------------------
__global__ __launch_bounds__(256)
void merge_rows(const u64* __restrict__ part, int* __restrict__ idx,
                int* __restrict__ flags, u64* __restrict__ rmin) {
  const int row = blockIdx.x * 4 + (threadIdx.x >> 6);
  const int lane = threadIdx.x & 63;
  const u64* p = part + ((size_t)row << 7);
  u64 a = p[lane], b = p[lane + 64];
  u64 p1 = umin64(a, b), p2 = umax64(a, b);
#pragma unroll
  for (int mm = 1; mm < 64; mm <<= 1) {
    u64 o1 = __shfl_xor(p1, mm);
    u64 o2 = __shfl_xor(p2, mm);
    u64 lo = umin64(p1, o1), hi = umax64(p1, o1);
    p1 = lo; p2 = umin64(hi, umin64(p2, o2));
  }
  if (lane == 0) {
    idx[row] = (int)(p1 & 0xffffffffu);
    flags[row] = (unpackd(p2) - unpackd(p1) <= EPSM) ? 1 : 0;
    rmin[row] = ~0ull;
  }
}

// ---------------------------------------------------------------------------
// deterministic compaction of flagged rows (single block, LDS prefix scan).
// Thread t owns rows {i*256+t}; output order fixed by (t, i) -> deterministic.
// ---------------------------------------------------------------------------
__global__ __launch_bounds__(256)
void compact(const int* __restrict__ flags, int* __restrict__ flaglist,
             int* __restrict__ flagcnt) {
  __shared__ int sc[256];
  const int t = threadIdx.x;
  int cnt = 0;
  for (int i = 0; i < NR / 256; ++i) cnt += flags[i * 256 + t];
  sc[t] = cnt;
  __syncthreads();
#pragma unroll
  for (int off = 1; off < 256; off <<= 1) {
    int v = (t >= off) ? sc[t - off] : 0;
    __syncthreads();
    sc[t] += v;
    __syncthreads();
  }
  int pos = sc[t] - cnt;                 // exclusive prefix
  if (t == 255) *flagcnt = sc[255];
  for (int i = 0; i < NR / 256; ++i) {
    const int row = i * 256 + t;
    if (flags[row]) flaglist[pos++] = row;
  }
}

// ---------------------------------------------------------------------------
// exact f32 rescan: unit = (flagged row, 256-code chunk); 32 units per row.
// One code per thread; z row staged in LDS (broadcast reads).
// ---------------------------------------------------------------------------
__global__ __launch_bounds__(256)
void rescue2(const float* __restrict__ z, const float* __restrict__ emb,
             const float* __restrict__ e2, const int* __restrict__ flaglist,
             const int* __restrict__ flagcnt, u64* __restrict__ rmin) {
  __shared__ float zr[D];
  __shared__ u64 red[4];
  const int tid = threadIdx.x, wave = tid >> 6, lane = tid & 63;
  const int total = (*flagcnt) * 32;
  for (int u = blockIdx.x; u < total; u += gridDim.x) {
    const int row = flaglist[u >> 5];
    const int code = ((u & 31) << 8) + tid;
    for (int i = tid; i < D / 4; i += 256)
      ((float4*)zr)[i] = ((const float4*)(z + (size_t)row * D))[i];
    __syncthreads();
    const float4* e4 = (const float4*)(emb + (size_t)code * D);
    float dot = 0.f;
#pragma unroll 8
    for (int i = 0; i < D / 4; ++i) {
      float4 ev = e4[i];
      float4 zv = ((const float4*)zr)[i];
      dot = fmaf(ev.x, zv.x, dot); dot = fmaf(ev.y, zv.y, dot);
      dot = fmaf(ev.z, zv.z, dot); dot = fmaf(ev.w, zv.w, dot);
    }
    u64 best = packdi(e2[code] - 2.f * dot, code);
#pragma unroll
    for (int mm = 1; mm < 64; mm <<= 1) best = umin64(best, __shfl_xor(best, mm));
    if (lane == 0) red[wave] = best;
    __syncthreads();
    if (tid == 0) {
      best = umin64(umin64(red[0], red[1]), umin64(red[2], red[3]));
      atomicMin(&rmin[row], best);
    }
    __syncthreads();   // also guards zr overwrite next iteration
  }
}

__global__ __launch_bounds__(256)
void fixup(const int* __restrict__ flags, const u64* __restrict__ rmin,
           int* __restrict__ idx) {
  const int row = blockIdx.x * 256 + threadIdx.x;
  if (row < NR && flags[row]) idx[row] = (int)(rmin[row] & 0xffffffffu);
}

// ---------------------------------------------------------------------------
// fallback f32 distance+argmin (round-1 kernel, used only if ws too small)
// ---------------------------------------------------------------------------
__global__ __launch_bounds__(256, 2)
void dist_argmin(const float* __restrict__ z, const float* __restrict__ emb,
                 const float* __restrict__ e2, int* __restrict__ out_idx) {
  __shared__ float As[16][68];
  __shared__ float Bs[16][132];
  const int tid = threadIdx.x;
  const int tx = tid & 15, ty = tid >> 4;
  const int rowBase = blockIdx.x * 64;
  const int a_row = tid >> 2, a_k = (tid & 3) << 2;
  const int b_row0 = tid >> 2, b_row1 = b_row0 + 64, b_k = a_k;
  const float* Aptr = z + (size_t)(rowBase + a_row) * D + a_k;
  float minval[4]; int minidx[4];
#pragma unroll
  for (int i = 0; i < 4; ++i) { minval[i] = INFINITY; minidx[i] = 0; }
  for (int ctile = 0; ctile < NE / 128; ++ctile) {
    const float* Bbase = emb + (size_t)ctile * 128 * D + b_k;
    float acc[4][8];
#pragma unroll
    for (int i = 0; i < 4; ++i)
#pragma unroll
      for (int j = 0; j < 8; ++j) acc[i][j] = 0.f;
    float4 pa = *reinterpret_cast<const float4*>(Aptr);
    float4 pb0 = *reinterpret_cast<const float4*>(Bbase + (size_t)b_row0 * D);
    float4 pb1 = *reinterpret_cast<const float4*>(Bbase + (size_t)b_row1 * D);
    for (int kt = 0; kt < D / 16; ++kt) {
      __syncthreads();
      As[a_k][a_row] = pa.x; As[a_k + 1][a_row] = pa.y;
      As[a_k + 2][a_row] = pa.z; As[a_k + 3][a_row] = pa.w;
      Bs[b_k][b_row0] = pb0.x; Bs[b_k + 1][b_row0] = pb0.y;
      Bs[b_k + 2][b_row0] = pb0.z; Bs[b_k + 3][b_row0] = pb0.w;
      Bs[b_k][b_row1] = pb1.x; Bs[b_k + 1][b_row1] = pb1.y;
      Bs[b_k + 2][b_row1] = pb1.z; Bs[b_k + 3][b_row1] = pb1.w;
      __syncthreads();
      if (kt + 1 < D / 16) {
        const int ko = (kt + 1) * 16;
        pa = *reinterpret_cast<const float4*>(Aptr + ko);
        pb0 = *reinterpret_cast<const float4*>(Bbase + (size_t)b_row0 * D + ko);
        pb1 = *reinterpret_cast<const float4*>(Bbase + (size_t)b_row1 * D + ko);
      }
#pragma unroll
      for (int k = 0; k < 16; ++k) {
        float a[4], b[8];
        *reinterpret_cast<float4*>(a) = *reinterpret_cast<const float4*>(&As[k][ty * 4]);
        *reinterpret_cast<float4*>(b) = *reinterpret_cast<const float4*>(&Bs[k][tx * 8]);
        *reinterpret_cast<float4*>(b + 4) = *reinterpret_cast<const float4*>(&Bs[k][tx * 8 + 4]);
#pragma unroll
        for (int i = 0; i < 4; ++i)
#pragma unroll
          for (int j = 0; j < 8; ++j) acc[i][j] = fmaf(a[i], b[j], acc[i][j]);
      }
    }
    float e2v[8];
    *reinterpret_cast<float4*>(e2v) = *reinterpret_cast<const float4*>(&e2[ctile * 128 + tx * 8]);
    *reinterpret_cast<float4*>(e2v + 4) = *reinterpret_cast<const float4*>(&e2[ctile * 128 + tx * 8 + 4]);
#pragma unroll
    for (int i = 0; i < 4; ++i) {
      float bv = INFINITY; int bi = 0;
#pragma unroll
      for (int j = 0; j < 8; ++j) {
        float dd = fmaf(-2.f, acc[i][j], e2v[j]);
        int c = ctile * 128 + tx * 8 + j;
        if (dd < bv) { bv = dd; bi = c; }
      }
#pragma unroll
      for (int m = 1; m < 16; m <<= 1) {
        float ov = __shfl_xor(bv, m); int oi = __shfl_xor(bi, m);
        if (ov < bv || (ov == bv && oi < bi)) { bv = ov; bi = oi; }
      }
      if (bv < minval[i] || (bv == minval[i] && bi < minidx[i])) {
        minval[i] = bv; minidx[i] = bi;
      }
    }
  }
  if (tx == 0) {
#pragma unroll
    for (int i = 0; i < 4; ++i) out_idx[rowBase + ty * 4 + i] = minidx[i];
  }
}

// ---------------------------------------------------------------------------
// gather + rotation trick + loss (closed form per row)
// ---------------------------------------------------------------------------
__global__ __launch_bounds__(256)
void rotate_kernel(const float* __restrict__ z, const float* __restrict__ emb,
                   const int* __restrict__ idx, float* __restrict__ out,
                   float* __restrict__ loss_out) {
  const int wave = threadIdx.x >> 6, lane = threadIdx.x & 63;
  const int row = (blockIdx.x << 2) + wave;
  const float4* e4 = reinterpret_cast<const float4*>(z + (size_t)row * D);
  const int code = idx[row];
  const float4* t4 = reinterpret_cast<const float4*>(emb + (size_t)code * D);
  float4 ev[3], tv[3];
  float s2 = 0.f, t2 = 0.f, dz = 0.f;
#pragma unroll
  for (int i = 0; i < 3; ++i) {
    ev[i] = e4[i * 64 + lane];
    tv[i] = t4[i * 64 + lane];
    s2 += ev[i].x * ev[i].x + ev[i].y * ev[i].y + ev[i].z * ev[i].z + ev[i].w * ev[i].w;
    t2 += tv[i].x * tv[i].x + tv[i].y * tv[i].y + tv[i].z * tv[i].z + tv[i].w * tv[i].w;
    dz += ev[i].x * tv[i].x + ev[i].y * tv[i].y + ev[i].z * tv[i].z + ev[i].w * tv[i].w;
  }
#pragma unroll
  for (int m = 32; m; m >>= 1) {
    s2 += __shfl_xor(s2, m); t2 += __shfl_xor(t2, m); dz += __shfl_xor(dz, m);
  }
  const float ns = sqrtf(s2), ntg = sqrtf(t2);
  const float rns = 1.f / fmaxf(ns, EPSV);
  const float rnt = 1.f / fmaxf(ntg, EPSV);
  const float wn2 = s2 * rns * rns + 2.f * dz * rns * rnt + t2 * rnt * rnt;
  const float rnw = 1.f / fmaxf(sqrtf(wn2), EPSV);
  const float ew = (s2 * rns + dz * rnt) * rnw;
  const float eu = s2 * rns;
  const float scale = ntg * rns;
  const float c_e = (1.f - 2.f * ew * rnw * rns) * scale;
  const float c_t = (2.f * eu * rnt - 2.f * ew * rnw * rnt) * scale;
  float4* o4 = reinterpret_cast<float4*>(out + (size_t)row * D);
#pragma unroll
  for (int i = 0; i < 3; ++i) {
    float4 o;
    o.x = c_e * ev[i].x + c_t * tv[i].x;
    o.y = c_e * ev[i].y + c_t * tv[i].y;
    o.z = c_e * ev[i].z + c_t * tv[i].z;
    o.w = c_e * ev[i].w + c_t * tv[i].w;
    o4[i * 64 + lane] = o;
  }
  if (lane == 0) {
    const float rowloss = (s2 + t2 - 2.f * dz) * (2.f / (float)((size_t)NR * D));
    atomicAdd(loss_out, rowloss);
  }
}

// ---------------------------------------------------------------------------
extern "C" void kernel_launch(void* const* d_in, const int* in_sizes, int n_in,
                              void* d_out, int out_size, void* d_ws, size_t ws_size,
                              hipStream_t stream) {
  const float* z   = (const float*)d_in[0];
  const float* emb = (const float*)d_in[1];
  float* out  = (float*)d_out;
  float* loss = out + (size_t)NR * D;

  // ws layout
  char* w = (char*)d_ws;
  const size_t SZ_ZH = (size_t)NR * D * 2;
  const size_t SZ_EH = (size_t)NE * D * 2;
  const size_t SZ_PART = (size_t)NR * NCT * 2 * 8;
  ushort_t* zh = (ushort_t*)w;              w += SZ_ZH;
  ushort_t* zl = (ushort_t*)w;              w += SZ_ZH;
  ushort_t* eh = (ushort_t*)w;              w += SZ_EH;
  ushort_t* el = (ushort_t*)w;              w += SZ_EH;
  u64* part = (u64*)w;                      w += SZ_PART;
  float* e2 = (float*)w;                    w += (size_t)NE * 4;
  int* idx = (int*)w;                       w += (size_t)NR * 4;
  int* flags = (int*)w;                     w += (size_t)NR * 4;
  u64* rmin = (u64*)w;                      w += (size_t)NR * 8;
  int* flaglist = (int*)w;                  w += (size_t)NR * 4;
  int* flagcnt = (int*)w;                   w += 256;
  const size_t REQ = (size_t)(w - (char*)d_ws);

  hipMemsetAsync(loss, 0, sizeof(float), stream);

  if (ws_size >= REQ) {
    hipMemsetAsync(rmin, 0xFF, (size_t)NR * 8, stream);   // belt & braces
    split_bf16<<<(NR * D / 4 + 255) / 256, 256, 0, stream>>>(z, zh, zl, NR * D / 4);
    split_bf16<<<(NE * D / 4 + 255) / 256, 256, 0, stream>>>(emb, eh, el, NE * D / 4);
    e2_kernel<<<NE / 4, 256, 0, stream>>>(emb, e2);
    mfma_dist<<<(NR / 128) * NCT, 256, 0, stream>>>(zh, zl, eh, el, e2, part);
    merge_rows<<<NR / 4, 256, 0, stream>>>(part, idx, flags, rmin);
    compact<<<1, 256, 0, stream>>>(flags, flaglist, flagcnt);
    rescue2<<<4096, 256, 0, stream>>>(z, emb, e2, flaglist, flagcnt, rmin);
    fixup<<<NR / 256, 256, 0, stream>>>(flags, rmin, idx);
  } else {
    // fallback: f32 vector path (fits in tiny ws)
    int* fidx = (int*)d_ws;
    float* fe2 = (float*)((char*)d_ws + (size_t)NR * 4);
    e2_kernel<<<NE / 4, 256, 0, stream>>>(emb, fe2);
    dist_argmin<<<NR / 64, 256, 0, stream>>>(z, emb, fe2, fidx);
    rotate_kernel<<<NR / 4, 256, 0, stream>>>(z, emb, fidx, out, loss);
    return;
  }
  rotate_kernel<<<NR / 4, 256, 0, stream>>>(z, emb, idx, out, loss);
}